// Round 7
// baseline (339.982 us; speedup 1.0000x reference)
//
#include <hip/hip_runtime.h>

#define EPSV 1e-5f
#define EB 512            // edge-chunk blocks for counting-sort passes
#define NPB 256           // nodes per bucket (bucket = dst >> 8)
#define NBUK_MAX 512      // supports N up to 131072

typedef __attribute__((ext_vector_type(8))) short bf16x8;
typedef __attribute__((ext_vector_type(4))) float f32x4;
typedef unsigned short ushort_t;

// ---- f32 -> bf16 round-to-nearest-even ----
__device__ inline unsigned f2bf(float f){
  unsigned u = __float_as_uint(f);
  u += 0x7fffu + ((u>>16)&1u);
  return u>>16;
}
#define BF_LO(u) __uint_as_float((u)<<16)
#define BF_HI(u) __uint_as_float((u)&0xffff0000u)
__device__ inline float bfu(unsigned short u){ return __uint_as_float(((unsigned)u)<<16); }

// ================= CSR build (two-level counting sort, no global atomics) =================
__global__ __launch_bounds__(256) void k_csr_count(const int* __restrict__ dst, int E, int chunk,
                                                   int nbuk, int* __restrict__ cnt){
  __shared__ int hist[NBUK_MAX];
  int t = threadIdx.x, b = blockIdx.x;
  for(int k=t; k<nbuk; k+=256) hist[k]=0;
  __syncthreads();
  int lo = b*chunk, hi = lo+chunk < E ? lo+chunk : E;
  for(int i=lo+t; i<hi; i+=256) atomicAdd(&hist[dst[i]>>8], 1);
  __syncthreads();
  for(int k=t; k<nbuk; k+=256) cnt[(size_t)k*EB + b] = hist[k];
}

__global__ __launch_bounds__(1024) void k_scan_local(const int* __restrict__ v_in, int L,
                                                     int* __restrict__ loc, int* __restrict__ blk){
  __shared__ int ps[1024];
  int t = threadIdx.x;
  int i = blockIdx.x*1024 + t;
  int v = (i < L) ? v_in[i] : 0;
  ps[t] = v;
  __syncthreads();
  for(int off=1; off<1024; off<<=1){
    int u = (t>=off) ? ps[t-off] : 0;
    __syncthreads();
    ps[t] += u;
    __syncthreads();
  }
  if(i < L) loc[i] = ps[t] - v;
  if(t == 1023) blk[blockIdx.x] = ps[t];
}

__global__ __launch_bounds__(1024) void k_scan_sums(int* __restrict__ blk, int nb,
                                                    int* __restrict__ totalOut){
  __shared__ int ps[1024];
  int t = threadIdx.x;
  int v = (t < nb) ? blk[t] : 0;
  ps[t] = v;
  __syncthreads();
  for(int off=1; off<1024; off<<=1){
    int u = (t>=off) ? ps[t-off] : 0;
    __syncthreads();
    ps[t] += u;
    __syncthreads();
  }
  if(t < nb) blk[t] = ps[t] - v;
  if(t == 1023) *totalOut = ps[t];
}

__global__ void k_scan_add2(const int* __restrict__ loc, const int* __restrict__ blk, int L,
                            int* __restrict__ pos){
  int i = blockIdx.x*256 + threadIdx.x;
  if(i < L) pos[i] = loc[i] + blk[i>>10];
}

__global__ __launch_bounds__(256) void k_csr_scatter(const int* __restrict__ src,
                                                     const int* __restrict__ dst,
                                                     const int* __restrict__ pos, int E, int chunk,
                                                     int nbuk, uint2* __restrict__ ebuf){
  __shared__ int cur[NBUK_MAX];
  int t = threadIdx.x, b = blockIdx.x;
  for(int k=t; k<nbuk; k+=256) cur[k] = pos[(size_t)k*EB + b];
  __syncthreads();
  int lo = b*chunk, hi = lo+chunk < E ? lo+chunk : E;
  for(int i=lo+t; i<hi; i+=256){
    int d = dst[i];
    int p = atomicAdd(&cur[d>>8], 1);
    ebuf[p] = make_uint2((unsigned)src[i], (unsigned)d);
  }
}

__global__ __launch_bounds__(256) void k_csr_final(const uint2* __restrict__ ebuf,
                                                   const int* __restrict__ pos,
                                                   int nbuk, int N, int E,
                                                   int* __restrict__ rp, float* __restrict__ dis,
                                                   int* __restrict__ csr_src){
  __shared__ int hist[NPB], ps[NPB], cur[NPB];
  int t = threadIdx.x, k = blockIdx.x;
  int base = pos[(size_t)k*EB];
  int next = (k+1 < nbuk) ? pos[(size_t)(k+1)*EB] : E;
  int cntk = next - base;
  int node0 = k*NPB;
  hist[t] = 0;
  __syncthreads();
  for(int i=t; i<cntk; i+=256) atomicAdd(&hist[(int)ebuf[base+i].y - node0], 1);
  __syncthreads();
  int deg = hist[t];
  ps[t] = deg;
  __syncthreads();
  for(int off=1; off<256; off<<=1){
    int u = (t>=off) ? ps[t-off] : 0;
    __syncthreads();
    ps[t] += u;
    __syncthreads();
  }
  int lb = ps[t] - deg;
  int n = node0 + t;
  if(n < N){
    rp[n]  = base + lb;
    dis[n] = rsqrtf((float)deg + 1.0f);
  }
  cur[t] = base + lb;
  __syncthreads();
  for(int i=t; i<cntk; i+=256){
    uint2 e = ebuf[base+i];
    int p = atomicAdd(&cur[(int)e.y - node0], 1);
    csr_src[p] = (int)e.x;
  }
  if(k == nbuk-1 && t == 0) rp[N] = E;
}

// ================= layer-1 GEMM (f32 VALU): P = bf16((x @ W1) * dis[row]) =================
__global__ __launch_bounds__(256) void k_gemm1(const float* __restrict__ x,
                                               const float* __restrict__ W,
                                               const float* __restrict__ dis,
                                               int N, ushort_t* __restrict__ Pu){
  __shared__ __align__(16) float Ws[32*16];
  int t = threadIdx.x;
  for(int i=t; i<32*16; i+=256) Ws[i] = W[i];
  __syncthreads();
  int row = blockIdx.x*256 + t;
  if(row >= N) return;
  const float4* xr = (const float4*)(x + (size_t)row*32);
  float acc[16];
  #pragma unroll
  for(int j=0;j<16;j++) acc[j]=0.f;
  #pragma unroll
  for(int k4=0;k4<8;k4++){
    float4 v = xr[k4];
    float vv[4] = {v.x, v.y, v.z, v.w};
    #pragma unroll
    for(int kk=0;kk<4;kk++){
      float h = vv[kk];
      const float* wr = &Ws[(k4*4+kk)*16];
      #pragma unroll
      for(int j=0;j<16;j++) acc[j] += h*wr[j];
    }
  }
  float d = dis[row];
  unsigned q[8];
  #pragma unroll
  for(int j=0;j<8;j++)
    q[j] = f2bf(acc[2*j]*d) | (f2bf(acc[2*j+1]*d)<<16);
  uint4* o = (uint4*)(Pu + (size_t)row*16);
  o[0] = make_uint4(q[0],q[1],q[2],q[3]);
  o[1] = make_uint4(q[4],q[5],q[6],q[7]);
}

// ================= weight prep: W' = sc .* W (bf16, MFMA-frag-packed), c' = sh @ W =================
// frag packing consistent with A-frag: lane l supplies (dim=l&15, kblock=l>>4), elems k=kb*8+e(+32*half)
template<int CINP, int CIN>
__global__ __launch_bounds__(256) void k_wprep(const float* __restrict__ W,
                                               const float* __restrict__ stats,
                                               ushort_t* __restrict__ wf, float* __restrict__ cp){
  constexpr int HALVES = CINP/32;
  int t = threadIdx.x;
  int total = 4*HALVES*64*8;
  for(int idx=t; idx<total; idx+=256){
    int e = idx & 7;
    int l = (idx>>3) & 63;
    int slot = idx>>9;             // ct*HALVES + half
    int ct = slot/HALVES, half = slot%HALVES;
    int k = (l>>4)*8 + e + half*32;
    int col = ct*16 + (l&15);
    float v = (k < CIN) ? stats[k]*W[k*64 + col] : 0.f;
    wf[idx] = (ushort_t)f2bf(v);
  }
  if(t < 64){
    float s = 0.f;
    for(int k=0;k<CIN;k++) s += stats[CIN+k]*W[k*64 + t];
    cp[t] = s;
  }
}

// ================= MFMA GEMM: P = bf16((A @ W' + c') * dis[row]), A bf16 [N][CINP] =================
template<int CINP>
__global__ __launch_bounds__(256) void k_gemm_mfma(const ushort_t* __restrict__ Au,
                                                   const ushort_t* __restrict__ wf,
                                                   const float* __restrict__ cp,
                                                   const float* __restrict__ dis,
                                                   int N, ushort_t* __restrict__ Pu){
  constexpr int HALVES = CINP/32;
  int t = threadIdx.x, wid = t>>6, l = t&63;
  int r0 = blockIdx.x*128 + wid*32;

  bf16x8 bfr[4][HALVES];
  #pragma unroll
  for(int ct=0; ct<4; ct++)
    #pragma unroll
    for(int h=0; h<HALVES; h++)
      bfr[ct][h] = *(const bf16x8*)(wf + ((size_t)(ct*HALVES+h)*64 + l)*8);

  bf16x8 af[2][HALVES];
  #pragma unroll
  for(int rt=0; rt<2; rt++){
    int arow = r0 + rt*16 + (l&15);
    #pragma unroll
    for(int h=0; h<HALVES; h++){
      if(arow < N) af[rt][h] = *(const bf16x8*)(Au + (size_t)arow*CINP + (l>>4)*8 + h*32);
      else         af[rt][h] = (bf16x8){0,0,0,0,0,0,0,0};
    }
  }

  f32x4 acc[2][4];
  #pragma unroll
  for(int rt=0; rt<2; rt++)
    #pragma unroll
    for(int ct=0; ct<4; ct++)
      acc[rt][ct] = (f32x4){0.f,0.f,0.f,0.f};

  #pragma unroll
  for(int rt=0; rt<2; rt++)
    #pragma unroll
    for(int ct=0; ct<4; ct++)
      #pragma unroll
      for(int h=0; h<HALVES; h++)
        acc[rt][ct] = __builtin_amdgcn_mfma_f32_16x16x32_bf16(af[rt][h], bfr[ct][h], acc[rt][ct], 0, 0, 0);

  // C/D: col = lane&15, row = (lane>>4)*4 + reg   [verified mapping]
  #pragma unroll
  for(int rt=0; rt<2; rt++){
    int rbase = r0 + rt*16 + (l>>4)*4;
    #pragma unroll
    for(int reg=0; reg<4; reg++){
      int row = rbase + reg;
      if(row < N){
        float d = dis[row];
        #pragma unroll
        for(int ct=0; ct<4; ct++){
          int col = ct*16 + (l&15);
          Pu[(size_t)row*64 + col] = (ushort_t)f2bf((acc[rt][ct][reg] + cp[col])*d);
        }
      }
    }
  }
}

// ================= gather: A = bf16(tanh(dis[n]*(P[n]+sum P[s]) + bias)), fused BN stats =================
template<int C, int OUTS, bool STATS>
__global__ __launch_bounds__(256) void k_gather(const int* __restrict__ rp,
    const int* __restrict__ csr_src,
    const float* __restrict__ dis, const ushort_t* __restrict__ Pu,
    const float* __restrict__ bias, int N, ushort_t* __restrict__ Au,
    float* __restrict__ colsum, float* __restrict__ colsq, int nblk){
  constexpr int GP = C/8;
  int t = threadIdx.x;
  int idx = blockIdx.x*256 + t;
  int n = idx / GP, g = idx % GP;
  bool valid = (n < N);
  float v[8];
  #pragma unroll
  for(int j=0;j<8;j++) v[j]=0.f;

  if(valid){
    int beg = rp[n], end = rp[n+1];
    const uint4* Pv = (const uint4*)Pu;
    uint4 u = Pv[(size_t)n*GP + g];   // self row
    float a0 = BF_LO(u.x), a1 = BF_HI(u.x), a2 = BF_LO(u.y), a3 = BF_HI(u.y);
    float a4 = BF_LO(u.z), a5 = BF_HI(u.z), a6 = BF_LO(u.w), a7 = BF_HI(u.w);
    float b0=0.f,b1=0.f,b2=0.f,b3=0.f,b4=0.f,b5=0.f,b6=0.f,b7=0.f;
    int j = beg;
    for(; j+1 < end; j += 2){
      int s0 = csr_src[j], s1 = csr_src[j+1];
      uint4 u0 = Pv[(size_t)s0*GP + g];
      uint4 u1 = Pv[(size_t)s1*GP + g];
      a0 += BF_LO(u0.x); a1 += BF_HI(u0.x); a2 += BF_LO(u0.y); a3 += BF_HI(u0.y);
      a4 += BF_LO(u0.z); a5 += BF_HI(u0.z); a6 += BF_LO(u0.w); a7 += BF_HI(u0.w);
      b0 += BF_LO(u1.x); b1 += BF_HI(u1.x); b2 += BF_LO(u1.y); b3 += BF_HI(u1.y);
      b4 += BF_LO(u1.z); b5 += BF_HI(u1.z); b6 += BF_LO(u1.w); b7 += BF_HI(u1.w);
    }
    if(j < end){
      int s0 = csr_src[j];
      uint4 u0 = Pv[(size_t)s0*GP + g];
      a0 += BF_LO(u0.x); a1 += BF_HI(u0.x); a2 += BF_LO(u0.y); a3 += BF_HI(u0.y);
      a4 += BF_LO(u0.z); a5 += BF_HI(u0.z); a6 += BF_LO(u0.w); a7 += BF_HI(u0.w);
    }
    float d = dis[n];
    float4 bb0 = *(const float4*)(bias + g*8);
    float4 bb1 = *(const float4*)(bias + g*8 + 4);
    v[0] = tanhf((a0+b0)*d + bb0.x); v[1] = tanhf((a1+b1)*d + bb0.y);
    v[2] = tanhf((a2+b2)*d + bb0.z); v[3] = tanhf((a3+b3)*d + bb0.w);
    v[4] = tanhf((a4+b4)*d + bb1.x); v[5] = tanhf((a5+b5)*d + bb1.y);
    v[6] = tanhf((a6+b6)*d + bb1.z); v[7] = tanhf((a7+b7)*d + bb1.w);

    uint4 o;
    o.x = f2bf(v[0]) | (f2bf(v[1])<<16);
    o.y = f2bf(v[2]) | (f2bf(v[3])<<16);
    o.z = f2bf(v[4]) | (f2bf(v[5])<<16);
    o.w = f2bf(v[6]) | (f2bf(v[7])<<16);
    *(uint4*)(Au + (size_t)n*OUTS + g*8) = o;
    if(OUTS > C){
      uint4 z = make_uint4(0,0,0,0);
      *(uint4*)(Au + (size_t)n*OUTS + C + g*8) = z;   // zero K-padding
    }
  }

  if(STATS){
    int lane = t & 63, wid = t >> 6;
    __shared__ float redS[4][GP][8], redQ[4][GP][8];
    #pragma unroll
    for(int j=0;j<8;j++){
      float s = v[j], q = v[j]*v[j];
      #pragma unroll
      for(int off=32; off>=GP; off>>=1){
        s += __shfl_down(s, off, 64);
        q += __shfl_down(q, off, 64);
      }
      if(lane < GP){ redS[wid][lane][j] = s; redQ[wid][lane][j] = q; }
    }
    __syncthreads();
    if(t < C){
      int gg = t>>3, j = t&7;
      float S = redS[0][gg][j]+redS[1][gg][j]+redS[2][gg][j]+redS[3][gg][j];
      float Q = redQ[0][gg][j]+redQ[1][gg][j]+redQ[2][gg][j]+redQ[3][gg][j];
      colsum[(size_t)t*nblk + blockIdx.x] = S;
      colsq [(size_t)t*nblk + blockIdx.x] = Q;
    }
  }
}

// ================= finalize BN scale/shift from per-block column partials =================
template<int C>
__global__ __launch_bounds__(1024) void k_bn_final2(const float* __restrict__ colsum,
                           const float* __restrict__ colsq,
                           const float* __restrict__ gw, const float* __restrict__ be,
                           float invN, int nblk, float* __restrict__ stats){
  constexpr int CH = 1024/C;
  int t = threadIdx.x;
  int c = t % C, ch = t / C;
  float S=0.f, Q=0.f;
  for(int b=ch; b<nblk; b+=CH){
    S += colsum[(size_t)c*nblk + b];
    Q += colsq [(size_t)c*nblk + b];
  }
  __shared__ float fs[1024], fq[1024];
  fs[t]=S; fq[t]=Q;
  __syncthreads();
  if(t < C){
    float St=fs[t], Qt=fq[t];
    for(int g=1; g<CH; g++){ St += fs[g*C+t]; Qt += fq[g*C+t]; }
    float m = St*invN;
    float var = fmaxf(Qt*invN - m*m, 0.f);
    float inv = rsqrtf(var + EPSV);
    float sc = gw[t]*inv;
    stats[t]   = sc;
    stats[C+t] = be[t] - m*sc;
  }
}

// ================= mean-pool per graph + linear head (A bf16) =================
__global__ __launch_bounds__(256) void k_pool(const ushort_t* __restrict__ Au,
                                              const int* __restrict__ batch, int N,
                                              const float* __restrict__ Wc,
                                              const float* __restrict__ bc,
                                              float* __restrict__ out){
  int gId = blockIdx.x;
  int t = threadIdx.x;
  int lo=0, hi=N;
  while(lo<hi){ int mid=(lo+hi)>>1; if(batch[mid] < gId) lo=mid+1; else hi=mid; }
  int start = lo;
  lo=start; hi=N;
  while(lo<hi){ int mid=(lo+hi)>>1; if(batch[mid] < gId+1) lo=mid+1; else hi=mid; }
  int end = lo;

  int c = t & 63, rg = t >> 6;
  float s = 0.f;
  for(int r = start+rg; r < end; r += 4) s += bfu(Au[(size_t)r*64 + c]);
  __shared__ float ls[256];
  ls[t] = s;
  __syncthreads();
  if(t < 64){
    float tot = ls[t] + ls[64+t] + ls[128+t] + ls[192+t];
    float cnt = (float)(end - start);
    float mean = tot / fmaxf(cnt, 1.0f);
    float v = mean * Wc[t];
    #pragma unroll
    for(int o=32; o>0; o>>=1) v += __shfl_down(v, o, 64);
    if(t == 0) out[gId] = v + bc[0];
  }
}

// ================= host launch =================
extern "C" void kernel_launch(void* const* d_in, const int* in_sizes, int n_in,
                              void* d_out, int out_size, void* d_ws, size_t ws_size,
                              hipStream_t stream) {
  const float* x     = (const float*)d_in[0];
  const int*   ei    = (const int*)d_in[1];
  const int*   batch = (const int*)d_in[2];
  const float* W1 = (const float*)d_in[3];
  const float* b1 = (const float*)d_in[4];
  const float* g1 = (const float*)d_in[5];
  const float* be1= (const float*)d_in[6];
  const float* W2 = (const float*)d_in[7];
  const float* b2 = (const float*)d_in[8];
  const float* g2 = (const float*)d_in[9];
  const float* be2= (const float*)d_in[10];
  const float* W3 = (const float*)d_in[11];
  const float* b3 = (const float*)d_in[12];
  const float* Wc = (const float*)d_in[13];
  const float* bc = (const float*)d_in[14];

  int N = in_sizes[2];
  int E = in_sizes[1] / 2;
  int G = out_size;
  const int* srcp = ei;
  const int* dstp = ei + E;
  float* out = (float*)d_out;

  auto cdiv = [](long long a, long long b){ return (int)((a+b-1)/b); };
  int nbuk  = cdiv(N, NPB);
  int chunk = cdiv(E, EB);
  int L     = nbuk * EB;
  int nbL   = cdiv(L, 1024);
  int nblk16 = cdiv((long long)N*2, 256);
  int nblk64 = cdiv((long long)N*8, 256);

  char* w = (char*)d_ws;
  ushort_t* Au       = (ushort_t*)w; w += (size_t)N*64*2;
  ushort_t* Pu       = (ushort_t*)w; w += (size_t)N*64*2;
  float*    dis      = (float*)w;    w += (size_t)N*4;
  int*      row_ptr  = (int*)w;      w += (size_t)(N+1)*4;
  int*      csr_src  = (int*)w;      w += (size_t)E*4;
  uint2*    ebuf     = (uint2*)w;    w += (size_t)E*8;
  int*      cnt      = (int*)w;      w += (size_t)L*4;
  int*      pos      = (int*)w;      w += (size_t)L*4;
  int*      scan_loc = (int*)w;      w += (size_t)L*4;
  int*      scan_blk = (int*)w;      w += 1024*4;
  float*    colsum   = (float*)w;    w += (size_t)64*nblk64*4;
  float*    colsq    = (float*)w;    w += (size_t)64*nblk64*4;
  float*    stats    = (float*)w;    w += 512;
  ushort_t* wf       = (ushort_t*)w; w += 8*64*8*2;
  float*    cp       = (float*)w;    w += 64*4;

  // ---- CSR build ----
  k_csr_count<<<EB,256,0,stream>>>(dstp, E, chunk, nbuk, cnt);
  k_scan_local<<<nbL,1024,0,stream>>>(cnt, L, scan_loc, scan_blk);
  k_scan_sums<<<1,1024,0,stream>>>(scan_blk, nbL, row_ptr + N);
  k_scan_add2<<<cdiv(L,256),256,0,stream>>>(scan_loc, scan_blk, L, pos);
  k_csr_scatter<<<EB,256,0,stream>>>(srcp, dstp, pos, E, chunk, nbuk, ebuf);
  k_csr_final<<<nbuk,256,0,stream>>>(ebuf, pos, nbuk, N, E, row_ptr, dis, csr_src);

  // ---- Layer 1: 32 -> 16 (VALU f32 GEMM) ----
  k_gemm1<<<cdiv(N,256),256,0,stream>>>(x, W1, dis, N, Pu);
  k_gather<16,32,true><<<nblk16,256,0,stream>>>(row_ptr, csr_src, dis, Pu, b1, N, Au, colsum, colsq, nblk16);
  k_bn_final2<16><<<1,1024,0,stream>>>(colsum, colsq, g1, be1, 1.0f/N, nblk16, stats);

  // ---- Layer 2: 16 -> 64 (MFMA, BN folded into W'/c', K padded to 32) ----
  k_wprep<32,16><<<1,256,0,stream>>>(W2, stats, wf, cp);
  k_gemm_mfma<32><<<cdiv(N,128),256,0,stream>>>(Au, wf, cp, dis, N, Pu);
  k_gather<64,64,true><<<nblk64,256,0,stream>>>(row_ptr, csr_src, dis, Pu, b2, N, Au, colsum, colsq, nblk64);
  k_bn_final2<64><<<1,1024,0,stream>>>(colsum, colsq, g2, be2, 1.0f/N, nblk64, stats);

  // ---- Layer 3: 64 -> 64 (MFMA) ----
  k_wprep<64,64><<<1,256,0,stream>>>(W3, stats, wf, cp);
  k_gemm_mfma<64><<<cdiv(N,128),256,0,stream>>>(Au, wf, cp, dis, N, Pu);
  k_gather<64,64,false><<<nblk64,256,0,stream>>>(row_ptr, csr_src, dis, Pu, b3, N, Au, colsum, colsq, nblk64);

  // ---- Pool + head ----
  k_pool<<<G,256,0,stream>>>(Au, batch, N, Wc, bc, out);
}

// Round 8
// 225.031 us; speedup vs baseline: 1.5108x; 1.5108x over previous
//
#include <hip/hip_runtime.h>

#define EPSV 1e-5f
#define EB 512            // edge-chunk blocks for counting-sort passes
#define NPB 256           // nodes per bucket (bucket = dst >> 8)
#define NBUK_MAX 512      // supports N up to 131072

typedef __attribute__((ext_vector_type(8))) short bf16x8;
typedef __attribute__((ext_vector_type(4))) float f32x4;
typedef unsigned short ushort_t;

// ---- f32 -> bf16 round-to-nearest-even ----
__device__ inline unsigned f2bf(float f){
  unsigned u = __float_as_uint(f);
  u += 0x7fffu + ((u>>16)&1u);
  return u>>16;
}
#define BF_LO(u) __uint_as_float((u)<<16)
#define BF_HI(u) __uint_as_float((u)&0xffff0000u)
__device__ inline float bfu(unsigned short u){ return __uint_as_float(((unsigned)u)<<16); }

// ================= CSR build (two-level counting sort, no global atomics) =================
__global__ __launch_bounds__(256) void k_csr_count(const int* __restrict__ dst, int E, int chunk,
                                                   int nbuk, int* __restrict__ cnt){
  __shared__ int hist[NBUK_MAX];
  int t = threadIdx.x, b = blockIdx.x;
  for(int k=t; k<nbuk; k+=256) hist[k]=0;
  __syncthreads();
  int lo = b*chunk, hi = lo+chunk < E ? lo+chunk : E;
  for(int i=lo+t; i<hi; i+=256) atomicAdd(&hist[dst[i]>>8], 1);
  __syncthreads();
  for(int k=t; k<nbuk; k+=256) cnt[(size_t)k*EB + b] = hist[k];
}

__global__ __launch_bounds__(1024) void k_scan_local(const int* __restrict__ v_in, int L,
                                                     int* __restrict__ loc, int* __restrict__ blk){
  __shared__ int ps[1024];
  int t = threadIdx.x;
  int i = blockIdx.x*1024 + t;
  int v = (i < L) ? v_in[i] : 0;
  ps[t] = v;
  __syncthreads();
  for(int off=1; off<1024; off<<=1){
    int u = (t>=off) ? ps[t-off] : 0;
    __syncthreads();
    ps[t] += u;
    __syncthreads();
  }
  if(i < L) loc[i] = ps[t] - v;
  if(t == 1023) blk[blockIdx.x] = ps[t];
}

__global__ __launch_bounds__(1024) void k_scan_sums(int* __restrict__ blk, int nb,
                                                    int* __restrict__ totalOut){
  __shared__ int ps[1024];
  int t = threadIdx.x;
  int v = (t < nb) ? blk[t] : 0;
  ps[t] = v;
  __syncthreads();
  for(int off=1; off<1024; off<<=1){
    int u = (t>=off) ? ps[t-off] : 0;
    __syncthreads();
    ps[t] += u;
    __syncthreads();
  }
  if(t < nb) blk[t] = ps[t] - v;
  if(t == 1023) *totalOut = ps[t];
}

__global__ void k_scan_add2(const int* __restrict__ loc, const int* __restrict__ blk, int L,
                            int* __restrict__ pos){
  int i = blockIdx.x*256 + threadIdx.x;
  if(i < L) pos[i] = loc[i] + blk[i>>10];
}

__global__ __launch_bounds__(256) void k_csr_scatter(const int* __restrict__ src,
                                                     const int* __restrict__ dst,
                                                     const int* __restrict__ pos, int E, int chunk,
                                                     int nbuk, uint2* __restrict__ ebuf){
  __shared__ int cur[NBUK_MAX];
  int t = threadIdx.x, b = blockIdx.x;
  for(int k=t; k<nbuk; k+=256) cur[k] = pos[(size_t)k*EB + b];
  __syncthreads();
  int lo = b*chunk, hi = lo+chunk < E ? lo+chunk : E;
  for(int i=lo+t; i<hi; i+=256){
    int d = dst[i];
    int p = atomicAdd(&cur[d>>8], 1);
    ebuf[p] = make_uint2((unsigned)src[i], (unsigned)d);
  }
}

__global__ __launch_bounds__(256) void k_csr_final(const uint2* __restrict__ ebuf,
                                                   const int* __restrict__ pos,
                                                   int nbuk, int N, int E,
                                                   int* __restrict__ rp, float* __restrict__ dis,
                                                   int* __restrict__ csr_src){
  __shared__ int hist[NPB], ps[NPB], cur[NPB];
  int t = threadIdx.x, k = blockIdx.x;
  int base = pos[(size_t)k*EB];
  int next = (k+1 < nbuk) ? pos[(size_t)(k+1)*EB] : E;
  int cntk = next - base;
  int node0 = k*NPB;
  hist[t] = 0;
  __syncthreads();
  for(int i=t; i<cntk; i+=256) atomicAdd(&hist[(int)ebuf[base+i].y - node0], 1);
  __syncthreads();
  int deg = hist[t];
  ps[t] = deg;
  __syncthreads();
  for(int off=1; off<256; off<<=1){
    int u = (t>=off) ? ps[t-off] : 0;
    __syncthreads();
    ps[t] += u;
    __syncthreads();
  }
  int lb = ps[t] - deg;
  int n = node0 + t;
  if(n < N){
    rp[n]  = base + lb;
    dis[n] = rsqrtf((float)deg + 1.0f);
  }
  cur[t] = base + lb;
  __syncthreads();
  for(int i=t; i<cntk; i+=256){
    uint2 e = ebuf[base+i];
    int p = atomicAdd(&cur[(int)e.y - node0], 1);
    csr_src[p] = (int)e.x;
  }
  if(k == nbuk-1 && t == 0) rp[N] = E;
}

// ================= layer-1 GEMM (f32 VALU): P = bf16((x @ W1) * dis[row]) =================
__global__ __launch_bounds__(256) void k_gemm1(const float* __restrict__ x,
                                               const float* __restrict__ W,
                                               const float* __restrict__ dis,
                                               int N, ushort_t* __restrict__ Pu){
  __shared__ __align__(16) float Ws[32*16];
  int t = threadIdx.x;
  for(int i=t; i<32*16; i+=256) Ws[i] = W[i];
  __syncthreads();
  int row = blockIdx.x*256 + t;
  if(row >= N) return;
  const float4* xr = (const float4*)(x + (size_t)row*32);
  float acc[16];
  #pragma unroll
  for(int j=0;j<16;j++) acc[j]=0.f;
  #pragma unroll
  for(int k4=0;k4<8;k4++){
    float4 v = xr[k4];
    float vv[4] = {v.x, v.y, v.z, v.w};
    #pragma unroll
    for(int kk=0;kk<4;kk++){
      float h = vv[kk];
      const float* wr = &Ws[(k4*4+kk)*16];
      #pragma unroll
      for(int j=0;j<16;j++) acc[j] += h*wr[j];
    }
  }
  float d = dis[row];
  unsigned q[8];
  #pragma unroll
  for(int j=0;j<8;j++)
    q[j] = f2bf(acc[2*j]*d) | (f2bf(acc[2*j+1]*d)<<16);
  uint4* o = (uint4*)(Pu + (size_t)row*16);
  o[0] = make_uint4(q[0],q[1],q[2],q[3]);
  o[1] = make_uint4(q[4],q[5],q[6],q[7]);
}

// ================= weight prep: W' = sc .* W (bf16, MFMA-frag-packed), c' = sh @ W =================
template<int CINP, int CIN>
__global__ __launch_bounds__(256) void k_wprep(const float* __restrict__ W,
                                               const float* __restrict__ stats,
                                               ushort_t* __restrict__ wf, float* __restrict__ cp){
  constexpr int HALVES = CINP/32;
  int t = threadIdx.x;
  int total = 4*HALVES*64*8;
  for(int idx=t; idx<total; idx+=256){
    int e = idx & 7;
    int l = (idx>>3) & 63;
    int slot = idx>>9;             // ct*HALVES + half
    int ct = slot/HALVES, half = slot%HALVES;
    int k = (l>>4)*8 + e + half*32;
    int col = ct*16 + (l&15);
    float v = (k < CIN) ? stats[k]*W[k*64 + col] : 0.f;
    wf[idx] = (ushort_t)f2bf(v);
  }
  if(t < 64){
    float s = 0.f;
    for(int k=0;k<CIN;k++) s += stats[CIN+k]*W[k*64 + t];
    cp[t] = s;
  }
}

// ================= MFMA GEMM: P = bf16((A @ W' + c') * dis[row]), A bf16 [N][CINP] =================
template<int CINP>
__global__ __launch_bounds__(256) void k_gemm_mfma(const ushort_t* __restrict__ Au,
                                                   const ushort_t* __restrict__ wf,
                                                   const float* __restrict__ cp,
                                                   const float* __restrict__ dis,
                                                   int N, ushort_t* __restrict__ Pu){
  constexpr int HALVES = CINP/32;
  int t = threadIdx.x, wid = t>>6, l = t&63;
  int r0 = blockIdx.x*128 + wid*32;

  bf16x8 bfr[4][HALVES];
  #pragma unroll
  for(int ct=0; ct<4; ct++)
    #pragma unroll
    for(int h=0; h<HALVES; h++)
      bfr[ct][h] = *(const bf16x8*)(wf + ((size_t)(ct*HALVES+h)*64 + l)*8);

  bf16x8 af[2][HALVES];
  #pragma unroll
  for(int rt=0; rt<2; rt++){
    int arow = r0 + rt*16 + (l&15);
    #pragma unroll
    for(int h=0; h<HALVES; h++){
      if(arow < N) af[rt][h] = *(const bf16x8*)(Au + (size_t)arow*CINP + (l>>4)*8 + h*32);
      else         af[rt][h] = (bf16x8){0,0,0,0,0,0,0,0};
    }
  }

  f32x4 acc[2][4];
  #pragma unroll
  for(int rt=0; rt<2; rt++)
    #pragma unroll
    for(int ct=0; ct<4; ct++)
      acc[rt][ct] = (f32x4){0.f,0.f,0.f,0.f};

  #pragma unroll
  for(int rt=0; rt<2; rt++)
    #pragma unroll
    for(int ct=0; ct<4; ct++)
      #pragma unroll
      for(int h=0; h<HALVES; h++)
        acc[rt][ct] = __builtin_amdgcn_mfma_f32_16x16x32_bf16(af[rt][h], bfr[ct][h], acc[rt][ct], 0, 0, 0);

  // C/D: col = lane&15, row = (lane>>4)*4 + reg
  #pragma unroll
  for(int rt=0; rt<2; rt++){
    int rbase = r0 + rt*16 + (l>>4)*4;
    #pragma unroll
    for(int reg=0; reg<4; reg++){
      int row = rbase + reg;
      if(row < N){
        float d = dis[row];
        #pragma unroll
        for(int ct=0; ct<4; ct++){
          int col = ct*16 + (l&15);
          Pu[(size_t)row*64 + col] = (ushort_t)f2bf((acc[rt][ct][reg] + cp[col])*d);
        }
      }
    }
  }
}

// ================= gather: A = bf16(tanh(dis[n]*(P[n]+sum P[s]) + bias)), fused BN stats =================
// partials layout: [block][2C] (coalesced)
template<int C, int OUTS, bool STATS>
__global__ __launch_bounds__(256) void k_gather(const int* __restrict__ rp,
    const int* __restrict__ csr_src,
    const float* __restrict__ dis, const ushort_t* __restrict__ Pu,
    const float* __restrict__ bias, int N, ushort_t* __restrict__ Au,
    float* __restrict__ partials){
  constexpr int GP = C/8;
  int t = threadIdx.x;
  int idx = blockIdx.x*256 + t;
  int n = idx / GP, g = idx % GP;
  bool valid = (n < N);
  float v[8];
  #pragma unroll
  for(int j=0;j<8;j++) v[j]=0.f;

  if(valid){
    int beg = rp[n], end = rp[n+1];
    const uint4* Pv = (const uint4*)Pu;
    uint4 u = Pv[(size_t)n*GP + g];   // self row
    float a0 = BF_LO(u.x), a1 = BF_HI(u.x), a2 = BF_LO(u.y), a3 = BF_HI(u.y);
    float a4 = BF_LO(u.z), a5 = BF_HI(u.z), a6 = BF_LO(u.w), a7 = BF_HI(u.w);
    float b0=0.f,b1=0.f,b2=0.f,b3=0.f,b4=0.f,b5=0.f,b6=0.f,b7=0.f;
    int j = beg;
    for(; j+1 < end; j += 2){
      int s0 = csr_src[j], s1 = csr_src[j+1];
      uint4 u0 = Pv[(size_t)s0*GP + g];
      uint4 u1 = Pv[(size_t)s1*GP + g];
      a0 += BF_LO(u0.x); a1 += BF_HI(u0.x); a2 += BF_LO(u0.y); a3 += BF_HI(u0.y);
      a4 += BF_LO(u0.z); a5 += BF_HI(u0.z); a6 += BF_LO(u0.w); a7 += BF_HI(u0.w);
      b0 += BF_LO(u1.x); b1 += BF_HI(u1.x); b2 += BF_LO(u1.y); b3 += BF_HI(u1.y);
      b4 += BF_LO(u1.z); b5 += BF_HI(u1.z); b6 += BF_LO(u1.w); b7 += BF_HI(u1.w);
    }
    if(j < end){
      int s0 = csr_src[j];
      uint4 u0 = Pv[(size_t)s0*GP + g];
      a0 += BF_LO(u0.x); a1 += BF_HI(u0.x); a2 += BF_LO(u0.y); a3 += BF_HI(u0.y);
      a4 += BF_LO(u0.z); a5 += BF_HI(u0.z); a6 += BF_LO(u0.w); a7 += BF_HI(u0.w);
    }
    float d = dis[n];
    float4 bb0 = *(const float4*)(bias + g*8);
    float4 bb1 = *(const float4*)(bias + g*8 + 4);
    v[0] = tanhf((a0+b0)*d + bb0.x); v[1] = tanhf((a1+b1)*d + bb0.y);
    v[2] = tanhf((a2+b2)*d + bb0.z); v[3] = tanhf((a3+b3)*d + bb0.w);
    v[4] = tanhf((a4+b4)*d + bb1.x); v[5] = tanhf((a5+b5)*d + bb1.y);
    v[6] = tanhf((a6+b6)*d + bb1.z); v[7] = tanhf((a7+b7)*d + bb1.w);

    uint4 o;
    o.x = f2bf(v[0]) | (f2bf(v[1])<<16);
    o.y = f2bf(v[2]) | (f2bf(v[3])<<16);
    o.z = f2bf(v[4]) | (f2bf(v[5])<<16);
    o.w = f2bf(v[6]) | (f2bf(v[7])<<16);
    *(uint4*)(Au + (size_t)n*OUTS + g*8) = o;
    if(OUTS > C){
      uint4 z = make_uint4(0,0,0,0);
      *(uint4*)(Au + (size_t)n*OUTS + C + g*8) = z;   // zero K-padding
    }
  }

  if(STATS){
    int lane = t & 63, wid = t >> 6;
    __shared__ float redS[4][GP][8], redQ[4][GP][8];
    #pragma unroll
    for(int j=0;j<8;j++){
      float s = v[j], q = v[j]*v[j];
      #pragma unroll
      for(int off=32; off>=GP; off>>=1){
        s += __shfl_down(s, off, 64);
        q += __shfl_down(q, off, 64);
      }
      if(lane < GP){ redS[wid][lane][j] = s; redQ[wid][lane][j] = q; }
    }
    __syncthreads();
    if(t < C){
      int gg = t>>3, j = t&7;
      float S = redS[0][gg][j]+redS[1][gg][j]+redS[2][gg][j]+redS[3][gg][j];
      float Q = redQ[0][gg][j]+redQ[1][gg][j]+redQ[2][gg][j]+redQ[3][gg][j];
      partials[(size_t)blockIdx.x*2*C + t]     = S;
      partials[(size_t)blockIdx.x*2*C + C + t] = Q;
    }
  }
}

// ================= BN reduce stage 1: 64 blocks, coalesced row-major sweep =================
template<int C>
__global__ __launch_bounds__(256) void k_bn_red(const float* __restrict__ partials, int nblk,
                                                float* __restrict__ red){
  constexpr int W = 2*C;
  constexpr int RPF = 256/W;     // rows in flight per block
  int t = threadIdx.x;
  int c = t % W, r0 = t / W;
  float acc = 0.f;
  for(int r = blockIdx.x*RPF + r0; r < nblk; r += 64*RPF)
    acc += partials[(size_t)r*W + c];
  __shared__ float ls[256];
  ls[t] = acc;
  __syncthreads();
  if(t < W){
    float s = 0.f;
    #pragma unroll
    for(int k=0;k<RPF;k++) s += ls[k*W + t];
    red[blockIdx.x*W + t] = s;
  }
}

// ================= BN reduce stage 2 + finalize scale/shift =================
template<int C>
__global__ __launch_bounds__(256) void k_bn_fin(const float* __restrict__ red,
                           const float* __restrict__ gw, const float* __restrict__ be,
                           float invN, float* __restrict__ stats){
  constexpr int W = 2*C;
  int t = threadIdx.x;
  __shared__ float tot[W];
  if(t < W){
    float s = 0.f;
    for(int r=0;r<64;r++) s += red[r*W + t];
    tot[t] = s;
  }
  __syncthreads();
  if(t < C){
    float m = tot[t]*invN;
    float var = fmaxf(tot[C+t]*invN - m*m, 0.f);
    float inv = rsqrtf(var + EPSV);
    float sc = gw[t]*inv;
    stats[t]   = sc;
    stats[C+t] = be[t] - m*sc;
  }
}

// ================= mean-pool per graph + linear head (A bf16) =================
__global__ __launch_bounds__(256) void k_pool(const ushort_t* __restrict__ Au,
                                              const int* __restrict__ batch, int N,
                                              const float* __restrict__ Wc,
                                              const float* __restrict__ bc,
                                              float* __restrict__ out){
  int gId = blockIdx.x;
  int t = threadIdx.x;
  int lo=0, hi=N;
  while(lo<hi){ int mid=(lo+hi)>>1; if(batch[mid] < gId) lo=mid+1; else hi=mid; }
  int start = lo;
  lo=start; hi=N;
  while(lo<hi){ int mid=(lo+hi)>>1; if(batch[mid] < gId+1) lo=mid+1; else hi=mid; }
  int end = lo;

  int c = t & 63, rg = t >> 6;
  float s = 0.f;
  for(int r = start+rg; r < end; r += 4) s += bfu(Au[(size_t)r*64 + c]);
  __shared__ float ls[256];
  ls[t] = s;
  __syncthreads();
  if(t < 64){
    float tot = ls[t] + ls[64+t] + ls[128+t] + ls[192+t];
    float cnt = (float)(end - start);
    float mean = tot / fmaxf(cnt, 1.0f);
    float v = mean * Wc[t];
    #pragma unroll
    for(int o=32; o>0; o>>=1) v += __shfl_down(v, o, 64);
    if(t == 0) out[gId] = v + bc[0];
  }
}

// ================= host launch =================
extern "C" void kernel_launch(void* const* d_in, const int* in_sizes, int n_in,
                              void* d_out, int out_size, void* d_ws, size_t ws_size,
                              hipStream_t stream) {
  const float* x     = (const float*)d_in[0];
  const int*   ei    = (const int*)d_in[1];
  const int*   batch = (const int*)d_in[2];
  const float* W1 = (const float*)d_in[3];
  const float* b1 = (const float*)d_in[4];
  const float* g1 = (const float*)d_in[5];
  const float* be1= (const float*)d_in[6];
  const float* W2 = (const float*)d_in[7];
  const float* b2 = (const float*)d_in[8];
  const float* g2 = (const float*)d_in[9];
  const float* be2= (const float*)d_in[10];
  const float* W3 = (const float*)d_in[11];
  const float* b3 = (const float*)d_in[12];
  const float* Wc = (const float*)d_in[13];
  const float* bc = (const float*)d_in[14];

  int N = in_sizes[2];
  int E = in_sizes[1] / 2;
  int G = out_size;
  const int* srcp = ei;
  const int* dstp = ei + E;
  float* out = (float*)d_out;

  auto cdiv = [](long long a, long long b){ return (int)((a+b-1)/b); };
  int nbuk  = cdiv(N, NPB);
  int chunk = cdiv(E, EB);
  int L     = nbuk * EB;
  int nbL   = cdiv(L, 1024);
  int nblk16 = cdiv((long long)N*2, 256);
  int nblk64 = cdiv((long long)N*8, 256);

  char* w = (char*)d_ws;
  ushort_t* Au       = (ushort_t*)w; w += (size_t)N*64*2;
  ushort_t* Pu       = (ushort_t*)w; w += (size_t)N*64*2;
  float*    dis      = (float*)w;    w += (size_t)N*4;
  int*      row_ptr  = (int*)w;      w += (size_t)(N+1)*4;
  int*      csr_src  = (int*)w;      w += (size_t)E*4;
  uint2*    ebuf     = (uint2*)w;    w += (size_t)E*8;
  int*      cnt      = (int*)w;      w += (size_t)L*4;
  int*      pos      = (int*)w;      w += (size_t)L*4;
  int*      scan_loc = (int*)w;      w += (size_t)L*4;
  int*      scan_blk = (int*)w;      w += 1024*4;
  float*    partials = (float*)w;    w += (size_t)nblk64*128*4;
  float*    red      = (float*)w;    w += 64*128*4;
  float*    stats    = (float*)w;    w += 512;
  ushort_t* wf       = (ushort_t*)w; w += 8*64*8*2;
  float*    cp       = (float*)w;    w += 64*4;

  // ---- CSR build ----
  k_csr_count<<<EB,256,0,stream>>>(dstp, E, chunk, nbuk, cnt);
  k_scan_local<<<nbL,1024,0,stream>>>(cnt, L, scan_loc, scan_blk);
  k_scan_sums<<<1,1024,0,stream>>>(scan_blk, nbL, row_ptr + N);
  k_scan_add2<<<cdiv(L,256),256,0,stream>>>(scan_loc, scan_blk, L, pos);
  k_csr_scatter<<<EB,256,0,stream>>>(srcp, dstp, pos, E, chunk, nbuk, ebuf);
  k_csr_final<<<nbuk,256,0,stream>>>(ebuf, pos, nbuk, N, E, row_ptr, dis, csr_src);

  // ---- Layer 1: 32 -> 16 (VALU f32 GEMM) ----
  k_gemm1<<<cdiv(N,256),256,0,stream>>>(x, W1, dis, N, Pu);
  k_gather<16,32,true><<<nblk16,256,0,stream>>>(row_ptr, csr_src, dis, Pu, b1, N, Au, partials);
  k_bn_red<16><<<64,256,0,stream>>>(partials, nblk16, red);
  k_bn_fin<16><<<1,256,0,stream>>>(red, g1, be1, 1.0f/N, stats);

  // ---- Layer 2: 16 -> 64 (MFMA, BN folded into W'/c', K padded to 32) ----
  k_wprep<32,16><<<1,256,0,stream>>>(W2, stats, wf, cp);
  k_gemm_mfma<32><<<cdiv(N,128),256,0,stream>>>(Au, wf, cp, dis, N, Pu);
  k_gather<64,64,true><<<nblk64,256,0,stream>>>(row_ptr, csr_src, dis, Pu, b2, N, Au, partials);
  k_bn_red<64><<<64,256,0,stream>>>(partials, nblk64, red);
  k_bn_fin<64><<<1,256,0,stream>>>(red, g2, be2, 1.0f/N, stats);

  // ---- Layer 3: 64 -> 64 (MFMA) ----
  k_wprep<64,64><<<1,256,0,stream>>>(W3, stats, wf, cp);
  k_gemm_mfma<64><<<cdiv(N,128),256,0,stream>>>(Au, wf, cp, dis, N, Pu);
  k_gather<64,64,false><<<nblk64,256,0,stream>>>(row_ptr, csr_src, dis, Pu, b3, N, Au, partials);

  // ---- Pool + head ----
  k_pool<<<G,256,0,stream>>>(Au, batch, N, Wc, bc, out);
}

// Round 9
// 217.705 us; speedup vs baseline: 1.5617x; 1.0337x over previous
//
#include <hip/hip_runtime.h>

#define EPSV 1e-5f
#define EB 512            // edge-chunk blocks for counting-sort passes
#define NPB 256           // nodes per bucket (bucket = dst >> 8)
#define NBUK_MAX 512      // supports N up to 131072

typedef __attribute__((ext_vector_type(8))) short bf16x8;
typedef __attribute__((ext_vector_type(4))) float f32x4;
typedef unsigned short ushort_t;

// ---- f32 -> bf16 round-to-nearest-even ----
__device__ inline unsigned f2bf(float f){
  unsigned u = __float_as_uint(f);
  u += 0x7fffu + ((u>>16)&1u);
  return u>>16;
}
#define BF_LO(u) __uint_as_float((u)<<16)
#define BF_HI(u) __uint_as_float((u)&0xffff0000u)
__device__ inline float bfu(unsigned short u){ return __uint_as_float(((unsigned)u)<<16); }

// ================= CSR build (two-level counting sort, no global atomics) =================
__global__ __launch_bounds__(256) void k_csr_count(const int* __restrict__ dst, int E, int chunk,
                                                   int nbuk, int* __restrict__ cnt){
  __shared__ int hist[NBUK_MAX];
  int t = threadIdx.x, b = blockIdx.x;
  for(int k=t; k<nbuk; k+=256) hist[k]=0;
  __syncthreads();
  int lo = b*chunk, hi = lo+chunk < E ? lo+chunk : E;
  for(int i=lo+t; i<hi; i+=256) atomicAdd(&hist[dst[i]>>8], 1);
  __syncthreads();
  for(int k=t; k<nbuk; k+=256) cnt[(size_t)k*EB + b] = hist[k];
}

__global__ __launch_bounds__(1024) void k_scan_local(const int* __restrict__ v_in, int L,
                                                     int* __restrict__ loc, int* __restrict__ blk){
  __shared__ int ps[1024];
  int t = threadIdx.x;
  int i = blockIdx.x*1024 + t;
  int v = (i < L) ? v_in[i] : 0;
  ps[t] = v;
  __syncthreads();
  for(int off=1; off<1024; off<<=1){
    int u = (t>=off) ? ps[t-off] : 0;
    __syncthreads();
    ps[t] += u;
    __syncthreads();
  }
  if(i < L) loc[i] = ps[t] - v;
  if(t == 1023) blk[blockIdx.x] = ps[t];
}

__global__ __launch_bounds__(1024) void k_scan_sums(int* __restrict__ blk, int nb,
                                                    int* __restrict__ totalOut){
  __shared__ int ps[1024];
  int t = threadIdx.x;
  int v = (t < nb) ? blk[t] : 0;
  ps[t] = v;
  __syncthreads();
  for(int off=1; off<1024; off<<=1){
    int u = (t>=off) ? ps[t-off] : 0;
    __syncthreads();
    ps[t] += u;
    __syncthreads();
  }
  if(t < nb) blk[t] = ps[t] - v;
  if(t == 1023) *totalOut = ps[t];
}

// pass C: bucket-sort edges; packed payload (src<<8)|(dst&255); pos computed inline
__global__ __launch_bounds__(256) void k_csr_scatter(const int* __restrict__ src,
                                                     const int* __restrict__ dst,
                                                     const int* __restrict__ loc,
                                                     const int* __restrict__ blk,
                                                     int E, int chunk, int nbuk,
                                                     unsigned* __restrict__ epk){
  __shared__ int cur[NBUK_MAX];
  int t = threadIdx.x, b = blockIdx.x;
  for(int k=t; k<nbuk; k+=256){
    int i = k*EB + b;
    cur[k] = loc[i] + blk[i>>10];
  }
  __syncthreads();
  int lo = b*chunk, hi = lo+chunk < E ? lo+chunk : E;
  for(int i=lo+t; i<hi; i+=256){
    int d = dst[i];
    int p = atomicAdd(&cur[d>>8], 1);
    epk[p] = ((unsigned)src[i]<<8) | (unsigned)(d & 255);
  }
}

// pass D: per-bucket finalize (rp, dis, csr_src)
__global__ __launch_bounds__(256) void k_csr_final(const unsigned* __restrict__ epk,
                                                   const int* __restrict__ loc,
                                                   const int* __restrict__ blk,
                                                   int nbuk, int N, int E,
                                                   int* __restrict__ rp, float* __restrict__ dis,
                                                   int* __restrict__ csr_src){
  __shared__ int hist[NPB], ps[NPB], cur[NPB];
  int t = threadIdx.x, k = blockIdx.x;
  int i0 = k*EB;
  int base = loc[i0] + blk[i0>>10];
  int next;
  if(k+1 < nbuk){ int i1 = (k+1)*EB; next = loc[i1] + blk[i1>>10]; }
  else next = E;
  int cntk = next - base;
  int node0 = k*NPB;
  hist[t] = 0;
  __syncthreads();
  for(int i=t; i<cntk; i+=256) atomicAdd(&hist[(int)(epk[base+i] & 255u)], 1);
  __syncthreads();
  int deg = hist[t];
  ps[t] = deg;
  __syncthreads();
  for(int off=1; off<256; off<<=1){
    int u = (t>=off) ? ps[t-off] : 0;
    __syncthreads();
    ps[t] += u;
    __syncthreads();
  }
  int lb = ps[t] - deg;
  int n = node0 + t;
  if(n < N){
    rp[n]  = base + lb;
    dis[n] = rsqrtf((float)deg + 1.0f);
  }
  cur[t] = base + lb;
  __syncthreads();
  for(int i=t; i<cntk; i+=256){
    unsigned e = epk[base+i];
    int p = atomicAdd(&cur[(int)(e & 255u)], 1);
    csr_src[p] = (int)(e >> 8);
  }
}

// ================= layer-1 GEMM (f32 VALU): P = bf16((x @ W1) * dis[row]) =================
__global__ __launch_bounds__(256) void k_gemm1(const float* __restrict__ x,
                                               const float* __restrict__ W,
                                               const float* __restrict__ dis,
                                               int N, ushort_t* __restrict__ Pu){
  __shared__ __align__(16) float Ws[32*16];
  int t = threadIdx.x;
  for(int i=t; i<32*16; i+=256) Ws[i] = W[i];
  __syncthreads();
  int row = blockIdx.x*256 + t;
  if(row >= N) return;
  const float4* xr = (const float4*)(x + (size_t)row*32);
  float acc[16];
  #pragma unroll
  for(int j=0;j<16;j++) acc[j]=0.f;
  #pragma unroll
  for(int k4=0;k4<8;k4++){
    float4 v = xr[k4];
    float vv[4] = {v.x, v.y, v.z, v.w};
    #pragma unroll
    for(int kk=0;kk<4;kk++){
      float h = vv[kk];
      const float* wr = &Ws[(k4*4+kk)*16];
      #pragma unroll
      for(int j=0;j<16;j++) acc[j] += h*wr[j];
    }
  }
  float d = dis[row];
  unsigned q[8];
  #pragma unroll
  for(int j=0;j<8;j++)
    q[j] = f2bf(acc[2*j]*d) | (f2bf(acc[2*j+1]*d)<<16);
  uint4* o = (uint4*)(Pu + (size_t)row*16);
  o[0] = make_uint4(q[0],q[1],q[2],q[3]);
  o[1] = make_uint4(q[4],q[5],q[6],q[7]);
}

// ================= fused BN finalize + weight prep =================
// red[64][2C] -> (sc,sh) in LDS -> wf = sc.*W bf16 frag-packed, cp = sh @ W
template<int C, int CINP, int CIN>
__global__ __launch_bounds__(256) void k_bn_finprep(const float* __restrict__ red,
                           const float* __restrict__ gw, const float* __restrict__ be,
                           float invN, const float* __restrict__ W,
                           ushort_t* __restrict__ wf, float* __restrict__ cp){
  constexpr int HALVES = CINP/32;
  __shared__ float sum0[C], sum1[C], scf[C], shf[C];
  int t = threadIdx.x;
  if(t < 2*C){
    float s = 0.f;
    for(int r=0;r<64;r++) s += red[r*2*C + t];
    if(t < C) sum0[t] = s; else sum1[t-C] = s;
  }
  __syncthreads();
  if(t < C){
    float m = sum0[t]*invN;
    float var = fmaxf(sum1[t]*invN - m*m, 0.f);
    float inv = rsqrtf(var + EPSV);
    float s = gw[t]*inv;
    scf[t] = s;
    shf[t] = be[t] - m*s;
  }
  __syncthreads();
  int total = 4*HALVES*64*8;
  for(int idx=t; idx<total; idx+=256){
    int e = idx & 7;
    int l = (idx>>3) & 63;
    int slot = idx>>9;             // ct*HALVES + half
    int ct = slot/HALVES, half = slot%HALVES;
    int k = (l>>4)*8 + e + half*32;
    int col = ct*16 + (l&15);
    float v = (k < CIN) ? scf[k]*W[k*64 + col] : 0.f;
    wf[idx] = (ushort_t)f2bf(v);
  }
  if(t < 64){
    float s = 0.f;
    for(int k=0;k<CIN;k++) s += shf[k]*W[k*64 + t];
    cp[t] = s;
  }
}

// ================= MFMA GEMM: P = bf16((A @ W' + c') * dis[row]), A bf16 [N][CINA] =================
template<int CINP, int CINA>
__global__ __launch_bounds__(256) void k_gemm_mfma(const ushort_t* __restrict__ Au,
                                                   const ushort_t* __restrict__ wf,
                                                   const float* __restrict__ cp,
                                                   const float* __restrict__ dis,
                                                   int N, ushort_t* __restrict__ Pu){
  constexpr int HALVES = CINP/32;
  int t = threadIdx.x, wid = t>>6, l = t&63;
  int r0 = blockIdx.x*128 + wid*32;

  bf16x8 bfr[4][HALVES];
  #pragma unroll
  for(int ct=0; ct<4; ct++)
    #pragma unroll
    for(int h=0; h<HALVES; h++)
      bfr[ct][h] = *(const bf16x8*)(wf + ((size_t)(ct*HALVES+h)*64 + l)*8);

  bf16x8 af[2][HALVES];
  #pragma unroll
  for(int rt=0; rt<2; rt++){
    int arow = r0 + rt*16 + (l&15);
    int k0 = (l>>4)*8;
    #pragma unroll
    for(int h=0; h<HALVES; h++){
      int kk = k0 + h*32;
      if(arow < N && kk < CINA) af[rt][h] = *(const bf16x8*)(Au + (size_t)arow*CINA + kk);
      else                      af[rt][h] = (bf16x8){0,0,0,0,0,0,0,0};
    }
  }

  f32x4 acc[2][4];
  #pragma unroll
  for(int rt=0; rt<2; rt++)
    #pragma unroll
    for(int ct=0; ct<4; ct++)
      acc[rt][ct] = (f32x4){0.f,0.f,0.f,0.f};

  #pragma unroll
  for(int rt=0; rt<2; rt++)
    #pragma unroll
    for(int ct=0; ct<4; ct++)
      #pragma unroll
      for(int h=0; h<HALVES; h++)
        acc[rt][ct] = __builtin_amdgcn_mfma_f32_16x16x32_bf16(af[rt][h], bfr[ct][h], acc[rt][ct], 0, 0, 0);

  // C/D: col = lane&15, row = (lane>>4)*4 + reg
  #pragma unroll
  for(int rt=0; rt<2; rt++){
    int rbase = r0 + rt*16 + (l>>4)*4;
    #pragma unroll
    for(int reg=0; reg<4; reg++){
      int row = rbase + reg;
      if(row < N){
        float d = dis[row];
        #pragma unroll
        for(int ct=0; ct<4; ct++){
          int col = ct*16 + (l&15);
          Pu[(size_t)row*64 + col] = (ushort_t)f2bf((acc[rt][ct][reg] + cp[col])*d);
        }
      }
    }
  }
}

// ================= gather: A = bf16(tanh(dis[n]*(P[n]+sum P[s]) + bias)), fused BN stats =================
// A stride = C (no padding). partials layout: [block][2C] (coalesced)
template<int C, bool STATS>
__global__ __launch_bounds__(256) void k_gather(const int* __restrict__ rp,
    const int* __restrict__ csr_src,
    const float* __restrict__ dis, const ushort_t* __restrict__ Pu,
    const float* __restrict__ bias, int N, ushort_t* __restrict__ Au,
    float* __restrict__ partials){
  constexpr int GP = C/8;
  int t = threadIdx.x;
  int idx = blockIdx.x*256 + t;
  int n = idx / GP, g = idx % GP;
  bool valid = (n < N);
  float v[8];
  #pragma unroll
  for(int j=0;j<8;j++) v[j]=0.f;

  if(valid){
    int beg = rp[n], end = rp[n+1];
    const uint4* Pv = (const uint4*)Pu;
    uint4 u = Pv[(size_t)n*GP + g];   // self row
    float a0 = BF_LO(u.x), a1 = BF_HI(u.x), a2 = BF_LO(u.y), a3 = BF_HI(u.y);
    float a4 = BF_LO(u.z), a5 = BF_HI(u.z), a6 = BF_LO(u.w), a7 = BF_HI(u.w);
    float b0=0.f,b1=0.f,b2=0.f,b3=0.f,b4=0.f,b5=0.f,b6=0.f,b7=0.f;
    int j = beg;
    for(; j+1 < end; j += 2){
      int s0 = csr_src[j], s1 = csr_src[j+1];
      uint4 u0 = Pv[(size_t)s0*GP + g];
      uint4 u1 = Pv[(size_t)s1*GP + g];
      a0 += BF_LO(u0.x); a1 += BF_HI(u0.x); a2 += BF_LO(u0.y); a3 += BF_HI(u0.y);
      a4 += BF_LO(u0.z); a5 += BF_HI(u0.z); a6 += BF_LO(u0.w); a7 += BF_HI(u0.w);
      b0 += BF_LO(u1.x); b1 += BF_HI(u1.x); b2 += BF_LO(u1.y); b3 += BF_HI(u1.y);
      b4 += BF_LO(u1.z); b5 += BF_HI(u1.z); b6 += BF_LO(u1.w); b7 += BF_HI(u1.w);
    }
    if(j < end){
      int s0 = csr_src[j];
      uint4 u0 = Pv[(size_t)s0*GP + g];
      a0 += BF_LO(u0.x); a1 += BF_HI(u0.x); a2 += BF_LO(u0.y); a3 += BF_HI(u0.y);
      a4 += BF_LO(u0.z); a5 += BF_HI(u0.z); a6 += BF_LO(u0.w); a7 += BF_HI(u0.w);
    }
    float d = dis[n];
    float4 bb0 = *(const float4*)(bias + g*8);
    float4 bb1 = *(const float4*)(bias + g*8 + 4);
    v[0] = tanhf((a0+b0)*d + bb0.x); v[1] = tanhf((a1+b1)*d + bb0.y);
    v[2] = tanhf((a2+b2)*d + bb0.z); v[3] = tanhf((a3+b3)*d + bb0.w);
    v[4] = tanhf((a4+b4)*d + bb1.x); v[5] = tanhf((a5+b5)*d + bb1.y);
    v[6] = tanhf((a6+b6)*d + bb1.z); v[7] = tanhf((a7+b7)*d + bb1.w);

    uint4 o;
    o.x = f2bf(v[0]) | (f2bf(v[1])<<16);
    o.y = f2bf(v[2]) | (f2bf(v[3])<<16);
    o.z = f2bf(v[4]) | (f2bf(v[5])<<16);
    o.w = f2bf(v[6]) | (f2bf(v[7])<<16);
    *(uint4*)(Au + (size_t)n*C + g*8) = o;
  }

  if(STATS){
    int lane = t & 63, wid = t >> 6;
    __shared__ float redS[4][GP][8], redQ[4][GP][8];
    #pragma unroll
    for(int j=0;j<8;j++){
      float s = v[j], q = v[j]*v[j];
      #pragma unroll
      for(int off=32; off>=GP; off>>=1){
        s += __shfl_down(s, off, 64);
        q += __shfl_down(q, off, 64);
      }
      if(lane < GP){ redS[wid][lane][j] = s; redQ[wid][lane][j] = q; }
    }
    __syncthreads();
    if(t < C){
      int gg = t>>3, j = t&7;
      float S = redS[0][gg][j]+redS[1][gg][j]+redS[2][gg][j]+redS[3][gg][j];
      float Q = redQ[0][gg][j]+redQ[1][gg][j]+redQ[2][gg][j]+redQ[3][gg][j];
      partials[(size_t)blockIdx.x*2*C + t]     = S;
      partials[(size_t)blockIdx.x*2*C + C + t] = Q;
    }
  }
}

// ================= BN reduce stage 1: 64 blocks, coalesced row-major sweep =================
template<int C>
__global__ __launch_bounds__(256) void k_bn_red(const float* __restrict__ partials, int nblk,
                                                float* __restrict__ red){
  constexpr int W = 2*C;
  constexpr int RPF = 256/W;     // rows in flight per block
  int t = threadIdx.x;
  int c = t % W, r0 = t / W;
  float acc = 0.f;
  for(int r = blockIdx.x*RPF + r0; r < nblk; r += 64*RPF)
    acc += partials[(size_t)r*W + c];
  __shared__ float ls[256];
  ls[t] = acc;
  __syncthreads();
  if(t < W){
    float s = 0.f;
    #pragma unroll
    for(int k=0;k<RPF;k++) s += ls[k*W + t];
    red[blockIdx.x*W + t] = s;
  }
}

// ================= mean-pool per graph + linear head (A bf16) =================
__global__ __launch_bounds__(256) void k_pool(const ushort_t* __restrict__ Au,
                                              const int* __restrict__ batch, int N,
                                              const float* __restrict__ Wc,
                                              const float* __restrict__ bc,
                                              float* __restrict__ out){
  int gId = blockIdx.x;
  int t = threadIdx.x;
  int lo=0, hi=N;
  while(lo<hi){ int mid=(lo+hi)>>1; if(batch[mid] < gId) lo=mid+1; else hi=mid; }
  int start = lo;
  lo=start; hi=N;
  while(lo<hi){ int mid=(lo+hi)>>1; if(batch[mid] < gId+1) lo=mid+1; else hi=mid; }
  int end = lo;

  int c = t & 63, rg = t >> 6;
  float s = 0.f;
  for(int r = start+rg; r < end; r += 4) s += bfu(Au[(size_t)r*64 + c]);
  __shared__ float ls[256];
  ls[t] = s;
  __syncthreads();
  if(t < 64){
    float tot = ls[t] + ls[64+t] + ls[128+t] + ls[192+t];
    float cnt = (float)(end - start);
    float mean = tot / fmaxf(cnt, 1.0f);
    float v = mean * Wc[t];
    #pragma unroll
    for(int o=32; o>0; o>>=1) v += __shfl_down(v, o, 64);
    if(t == 0) out[gId] = v + bc[0];
  }
}

// ================= host launch =================
extern "C" void kernel_launch(void* const* d_in, const int* in_sizes, int n_in,
                              void* d_out, int out_size, void* d_ws, size_t ws_size,
                              hipStream_t stream) {
  const float* x     = (const float*)d_in[0];
  const int*   ei    = (const int*)d_in[1];
  const int*   batch = (const int*)d_in[2];
  const float* W1 = (const float*)d_in[3];
  const float* b1 = (const float*)d_in[4];
  const float* g1 = (const float*)d_in[5];
  const float* be1= (const float*)d_in[6];
  const float* W2 = (const float*)d_in[7];
  const float* b2 = (const float*)d_in[8];
  const float* g2 = (const float*)d_in[9];
  const float* be2= (const float*)d_in[10];
  const float* W3 = (const float*)d_in[11];
  const float* b3 = (const float*)d_in[12];
  const float* Wc = (const float*)d_in[13];
  const float* bc = (const float*)d_in[14];

  int N = in_sizes[2];
  int E = in_sizes[1] / 2;
  int G = out_size;
  const int* srcp = ei;
  const int* dstp = ei + E;
  float* out = (float*)d_out;

  auto cdiv = [](long long a, long long b){ return (int)((a+b-1)/b); };
  int nbuk  = cdiv(N, NPB);
  int chunk = cdiv(E, EB);
  int L     = nbuk * EB;
  int nbL   = cdiv(L, 1024);
  int nblk16 = cdiv((long long)N*2, 256);
  int nblk64 = cdiv((long long)N*8, 256);

  char* w = (char*)d_ws;
  ushort_t* Au       = (ushort_t*)w; w += (size_t)N*64*2;
  ushort_t* Pu       = (ushort_t*)w; w += (size_t)N*64*2;
  float*    dis      = (float*)w;    w += (size_t)N*4;
  int*      row_ptr  = (int*)w;      w += (size_t)(N+1)*4;
  int*      csr_src  = (int*)w;      w += (size_t)E*4;
  unsigned* epk      = (unsigned*)w; w += (size_t)E*4;
  int*      cnt      = (int*)w;      w += (size_t)L*4;
  int*      scan_loc = (int*)w;      w += (size_t)L*4;
  int*      scan_blk = (int*)w;      w += 1024*4;
  float*    partials = (float*)w;    w += (size_t)nblk64*128*4;
  float*    red      = (float*)w;    w += 64*128*4;
  ushort_t* wf       = (ushort_t*)w; w += 8*64*8*2;
  float*    cp       = (float*)w;    w += 64*4;

  // ---- CSR build ----
  k_csr_count<<<EB,256,0,stream>>>(dstp, E, chunk, nbuk, cnt);
  k_scan_local<<<nbL,1024,0,stream>>>(cnt, L, scan_loc, scan_blk);
  k_scan_sums<<<1,1024,0,stream>>>(scan_blk, nbL, row_ptr + N);
  k_csr_scatter<<<EB,256,0,stream>>>(srcp, dstp, scan_loc, scan_blk, E, chunk, nbuk, epk);
  k_csr_final<<<nbuk,256,0,stream>>>(epk, scan_loc, scan_blk, nbuk, N, E, row_ptr, dis, csr_src);

  // ---- Layer 1: 32 -> 16 (VALU f32 GEMM) ----
  k_gemm1<<<cdiv(N,256),256,0,stream>>>(x, W1, dis, N, Pu);
  k_gather<16,true><<<nblk16,256,0,stream>>>(row_ptr, csr_src, dis, Pu, b1, N, Au, partials);
  k_bn_red<16><<<64,256,0,stream>>>(partials, nblk16, red);
  k_bn_finprep<16,32,16><<<1,256,0,stream>>>(red, g1, be1, 1.0f/N, W2, wf, cp);

  // ---- Layer 2: 16 -> 64 (MFMA, BN folded into W'/c', A stored [N][16]) ----
  k_gemm_mfma<32,16><<<cdiv(N,128),256,0,stream>>>(Au, wf, cp, dis, N, Pu);
  k_gather<64,true><<<nblk64,256,0,stream>>>(row_ptr, csr_src, dis, Pu, b2, N, Au, partials);
  k_bn_red<64><<<64,256,0,stream>>>(partials, nblk64, red);
  k_bn_finprep<64,64,64><<<1,256,0,stream>>>(red, g2, be2, 1.0f/N, W3, wf, cp);

  // ---- Layer 3: 64 -> 64 (MFMA) ----
  k_gemm_mfma<64,64><<<cdiv(N,128),256,0,stream>>>(Au, wf, cp, dis, N, Pu);
  k_gather<64,false><<<nblk64,256,0,stream>>>(row_ptr, csr_src, dis, Pu, b3, N, Au, partials);

  // ---- Pool + head ----
  k_pool<<<G,256,0,stream>>>(Au, batch, N, Wc, bc, out);
}